// Round 3
// baseline (82059.778 us; speedup 1.0000x reference)
//
#include <hip/hip_runtime.h>
#include <math.h>

#define T_ 512

__device__ __forceinline__ double sigmd(double v) { return 1.0 / (1.0 + exp(-v)); }

// Monotonic group barrier: 128 blocks per group, counter never reset.
// target = 128 * barrier_number. Counters zeroed via hipMemsetAsync per launch.
__device__ __forceinline__ void group_barrier(unsigned* bar, unsigned target) {
  __threadfence();
  __syncthreads();
  if (threadIdx.x == 0) {
    __hip_atomic_fetch_add(bar, 1u, __ATOMIC_RELEASE, __HIP_MEMORY_SCOPE_AGENT);
    while (__hip_atomic_load(bar, __ATOMIC_ACQUIRE, __HIP_MEMORY_SCOPE_AGENT) < target) {
      __builtin_amdgcn_s_sleep(2);
    }
  }
  __syncthreads();
  __threadfence();
}

// Grid 512 = 4 groups x 128 col-blocks. Group g owns batch rows [64g, 64g+64).
// Block w owns H-cols {2w, 2w+1} (8 gate-cols) of BOTH layers.
// All recurrence math in fp64 (condition/prediction outputs are sign(logit) —
// fp32 accumulation-order noise flips booleans vs the np reference).
// Static LDS ~59.4 KB -> 2 blocks/CU -> all 512 blocks co-resident.
__global__ __launch_bounds__(256, 2) void lstm2_head(
    const float* __restrict__ x, const float* __restrict__ W1,
    const float* __restrict__ b1, const float* __restrict__ W2,
    const float* __restrict__ b2, const float* __restrict__ Wo,
    const float* __restrict__ bo, float* __restrict__ out,
    unsigned char* __restrict__ ws)
{
  __shared__ float  W1T[8 * 516];    // [c 0..7][k 0..511], fp32 (exact inputs)
  __shared__ float  W2T[8 * 516];
  __shared__ double inTd[64 * 34];   // [row 0..63][k 0..31], stride 34 doubles
  __shared__ double zTd[64 * 17];    // [row][lsel*8 + gate*2 + j], stride 17
  __shared__ double redd[32];

  const int tid = threadIdx.x;
  const int g  = blockIdx.x >> 7;     // 0..3
  const int w  = blockIdx.x & 127;    // 0..127
  const int b0 = g << 6;              // batch row base
  const int k0 = w << 1;              // H-col base

  unsigned* bar = (unsigned*)ws + (g << 4);             // 64B-spaced counters
  double* hbase = (double*)(ws + 1024);
  double* h1g = hbase + (size_t)g * 32768;              // [2][64][256] doubles
  double* h2g = hbase + 131072 + (size_t)g * 32768;

  // Stage weight slices transposed (fp32, exact): c = gate*2+j -> col gate*256+k0+j
  for (int idx = tid; idx < 4096; idx += 256) {
    int k = idx & 511;
    int c = idx >> 9;
    int col = ((c >> 1) << 8) + k0 + (c & 1);
    W1T[c * 516 + k] = W1[(size_t)k * 1024 + col];
    W2T[c * 516 + k] = W2[(size_t)k * 1024 + col];
  }

  // Zero initial-state slots (slot 1 holds h(-1))
  if (tid < 128) {
    h1g[16384 + (w << 7) + tid] = 0.0;
    h2g[16384 + (w << 7) + tid] = 0.0;
  }

  group_barrier(bar, 128u);   // barrier #1

  // GEMM thread mapping: col tx, rows {ry, 32+ry}, full K per thread
  const int tx = tid & 7;
  const int ry = tid >> 3;            // 0..31

  // Update thread mapping: one cell per thread
  const int urow = tid & 63;
  const int pair = tid >> 6;          // 0..3
  const int lsel = pair & 1;          // 0 = layer1, 1 = layer2
  const int uj   = pair >> 1;         // 0..1 col within block slice
  const float* bb = lsel ? b2 : b1;
  const double bz0 = (double)bb[k0 + uj];
  const double bz1 = (double)bb[256 + k0 + uj];
  const double bz2 = (double)bb[512 + k0 + uj];
  const double bz3 = (double)bb[768 + k0 + uj];
  double cst = 0.0;

  // Head weights (blocks w<64 handle batch row b0+w)
  double wo_r[6];
  if (w < 64) {
    #pragma unroll
    for (int c = 0; c < 6; ++c) wo_r[c] = (double)Wo[tid * 6 + c];
  }

  // Phase p: layer1(t=p), layer2(t=p-1), head(t=p-2).
  for (int p = 0; p <= T_ + 1; ++p) {
    const bool doL1 = (p < T_);
    const bool doL2 = (p >= 1) && (p <= T_);
    const int  xp   = doL1 ? p : (T_ - 1);
    const double* h1prev = h1g + (((p + 1) & 1) << 14);   // h1(p-1)
    const double* h2pp   = h2g + ((p & 1) << 14);         // h2(p-2)
    double* h1cur = h1g + ((p & 1) << 14);                // h1(p)
    double* h2cur = h2g + (((p + 1) & 1) << 14);          // h2(p-1)

    double acc1[2] = {0.0, 0.0};
    double acc2[2] = {0.0, 0.0};

    // Concat K-space [0,768): [0,256)=x_p, [256,512)=h1(p-1), [512,768)=h2(p-2)
    #pragma unroll 1
    for (int tile = 0; tile < 24; ++tile) {
      const int kb = tile << 5;
      #pragma unroll
      for (int rep = 0; rep < 4; ++rep) {    // stage inTd[64][32]
        int q  = (rep << 8) + tid;           // 0..1023 double2 slots
        int r  = q >> 4;                     // row 0..63
        int cq = (q & 15) << 1;              // k offset 0..30 step 2
        int kg = kb + cq;
        double2 v;
        if (kg < 256) {
          float2 xv = *(const float2*)(x + (((size_t)(b0 + r) * T_ + xp) << 8) + kg);
          v.x = (double)xv.x; v.y = (double)xv.y;
        } else if (kg < 512) {
          v = *(const double2*)(h1prev + (r << 8) + (kg - 256));
        } else {
          v = *(const double2*)(h2pp + (r << 8) + (kg - 512));
        }
        *(double2*)(inTd + r * 34 + cq) = v;
      }
      __syncthreads();
      const bool l1t = doL1 && (kb < 512);
      const bool l2t = doL2 && (kb >= 256);
      const float* wp1 = W1T + tx * 516 + kb;
      const float* wp2 = W2T + tx * 516 + (kb - 256);
      const double* ap0 = inTd + ry * 34;
      const double* ap1 = inTd + (32 + ry) * 34;
      if (l1t && l2t) {
        #pragma unroll
        for (int kk = 0; kk < 32; kk += 2) {
          double2 a0 = *(const double2*)(ap0 + kk);
          double2 a1 = *(const double2*)(ap1 + kk);
          float2 w1f = *(const float2*)(wp1 + kk);
          float2 w2f = *(const float2*)(wp2 + kk);
          double w1x = (double)w1f.x, w1y = (double)w1f.y;
          double w2x = (double)w2f.x, w2y = (double)w2f.y;
          acc1[0] = fma(a0.x, w1x, acc1[0]);
          acc1[0] = fma(a0.y, w1y, acc1[0]);
          acc1[1] = fma(a1.x, w1x, acc1[1]);
          acc1[1] = fma(a1.y, w1y, acc1[1]);
          acc2[0] = fma(a0.x, w2x, acc2[0]);
          acc2[0] = fma(a0.y, w2y, acc2[0]);
          acc2[1] = fma(a1.x, w2x, acc2[1]);
          acc2[1] = fma(a1.y, w2y, acc2[1]);
        }
      } else if (l1t) {
        #pragma unroll
        for (int kk = 0; kk < 32; kk += 2) {
          double2 a0 = *(const double2*)(ap0 + kk);
          double2 a1 = *(const double2*)(ap1 + kk);
          float2 w1f = *(const float2*)(wp1 + kk);
          double w1x = (double)w1f.x, w1y = (double)w1f.y;
          acc1[0] = fma(a0.x, w1x, acc1[0]);
          acc1[0] = fma(a0.y, w1y, acc1[0]);
          acc1[1] = fma(a1.x, w1x, acc1[1]);
          acc1[1] = fma(a1.y, w1y, acc1[1]);
        }
      } else if (l2t) {
        #pragma unroll
        for (int kk = 0; kk < 32; kk += 2) {
          double2 a0 = *(const double2*)(ap0 + kk);
          double2 a1 = *(const double2*)(ap1 + kk);
          float2 w2f = *(const float2*)(wp2 + kk);
          double w2x = (double)w2f.x, w2y = (double)w2f.y;
          acc2[0] = fma(a0.x, w2x, acc2[0]);
          acc2[0] = fma(a0.y, w2y, acc2[0]);
          acc2[1] = fma(a1.x, w2x, acc2[1]);
          acc2[1] = fma(a1.y, w2y, acc2[1]);
        }
      }
      __syncthreads();
    }

    // z exchange: [row][lsel*8 + c], c = tx
    if (doL1) {
      zTd[ry * 17 + tx]        = acc1[0];
      zTd[(32 + ry) * 17 + tx] = acc1[1];
    }
    if (doL2) {
      zTd[ry * 17 + 8 + tx]        = acc2[0];
      zTd[(32 + ry) * 17 + 8 + tx] = acc2[1];
    }
    __syncthreads();

    // Gate updates: gates (i, j, f, o), forget bias 1.0
    {
      const bool act = lsel ? doL2 : doL1;
      if (act) {
        const double* zr = zTd + urow * 17 + (lsel << 3);
        double zi = zr[uj]     + bz0;
        double zj = zr[2 + uj] + bz1;
        double zf = zr[4 + uj] + bz2;
        double zo = zr[6 + uj] + bz3;
        cst = cst * sigmd(zf + 1.0) + sigmd(zi) * tanh(zj);
        double hv = tanh(cst) * sigmd(zo);
        double* hdst = lsel ? h2cur : h1cur;
        hdst[(urow << 8) + k0 + uj] = hv;
      }
    }

    // Head: block w<64 handles batch row b0+w at t3 = p-2 (h2(t3) in slot p&1)
    const int t3 = p - 2;
    if (t3 >= 0 && w < 64) {
      const double* h2t3 = h2g + ((p & 1) << 14);
      double v = h2t3[(w << 8) + tid];
      double pr[6];
      #pragma unroll
      for (int c = 0; c < 6; ++c) pr[c] = v * wo_r[c];
      #pragma unroll
      for (int off = 32; off >= 1; off >>= 1) {
        #pragma unroll
        for (int c = 0; c < 6; ++c) pr[c] += __shfl_down(pr[c], off, 64);
      }
      if ((tid & 63) == 0) {
        #pragma unroll
        for (int c = 0; c < 6; ++c) redd[(tid >> 6) * 6 + c] = pr[c];
      }
      __syncthreads();
      if (tid < 6) {
        double lg = redd[tid] + redd[6 + tid] + redd[12 + tid] + redd[18 + tid]
                  + (double)bo[tid];
        size_t orow = (((size_t)(b0 + w)) << 9) + (size_t)t3;   // b*T + t
        out[orow * 6 + tid] = (float)lg;
        float pd = (lg > 0.0) ? 1.0f : 0.0f;   // 0.5 < sigmoid(lg) <=> lg > 0
        out[(size_t)786432 + orow * 6 + tid] = pd;    // condition
        out[(size_t)1572864 + orow * 6 + tid] = pd;   // prediction
      }
    }

    group_barrier(bar, ((unsigned)(p + 2)) << 7);
  }
}

extern "C" void kernel_launch(void* const* d_in, const int* in_sizes, int n_in,
                              void* d_out, int out_size, void* d_ws, size_t ws_size,
                              hipStream_t stream) {
  const float* x  = (const float*)d_in[0];
  const float* W1 = (const float*)d_in[1];
  const float* b1 = (const float*)d_in[2];
  const float* W2 = (const float*)d_in[3];
  const float* b2 = (const float*)d_in[4];
  const float* Wo = (const float*)d_in[5];
  const float* bo = (const float*)d_in[6];
  float* out = (float*)d_out;
  unsigned char* ws = (unsigned char*)d_ws;

  // Zero barrier counters (first 1 KB of ws); part of the captured graph.
  hipMemsetAsync(d_ws, 0, 1024, stream);

  lstm2_head<<<dim3(512), dim3(256), 0, stream>>>(x, W1, b1, W2, b2, Wo, bo, out, ws);
}

// Round 4
// 38922.165 us; speedup vs baseline: 2.1083x; 2.1083x over previous
//
#include <hip/hip_runtime.h>
#include <math.h>

#define T_ 512

__device__ __forceinline__ double sigmd(double v) { return 1.0 / (1.0 + exp(-v)); }

// Coherent (agent-scope, cache-bypassing) 8-byte load/store — no fences needed.
__device__ __forceinline__ double hload(const double* p) {
  unsigned long long u = __hip_atomic_load((const unsigned long long*)p,
                                           __ATOMIC_RELAXED, __HIP_MEMORY_SCOPE_AGENT);
  return __builtin_bit_cast(double, u);
}
__device__ __forceinline__ void hstore(double* p, double v) {
  __hip_atomic_store((unsigned long long*)p, __builtin_bit_cast(unsigned long long, v),
                     __ATOMIC_RELAXED, __HIP_MEMORY_SCOPE_AGENT);
}

// Light group barrier: 8 blocks/group, monotonic counter, no cache-nuking fences.
// Data is exchanged via relaxed agent atomics (coherent by construction); we only
// need (1) all prior memory ops drained before arrival (s_waitcnt in every wave,
// and __syncthreads itself drains), (2) compiler ordering (asm memory clobber).
__device__ __forceinline__ void light_barrier(unsigned* bar, unsigned target) {
  __builtin_amdgcn_s_waitcnt(0);   // every wave drains vm/lgkm before arrival
  __syncthreads();
  if (threadIdx.x == 0) {
    __hip_atomic_fetch_add(bar, 1u, __ATOMIC_RELAXED, __HIP_MEMORY_SCOPE_AGENT);
    while (__hip_atomic_load(bar, __ATOMIC_RELAXED, __HIP_MEMORY_SCOPE_AGENT) < target)
      __builtin_amdgcn_s_sleep(8);
    __asm__ volatile("" ::: "memory");
  }
  __syncthreads();
}

// Grid 256 = 32 groups x 8 blocks; block = (g*8 + w) so XCD (blockIdx%8) == w
// caches only w's 512 KB weight slice in its L2. Group g owns batch rows
// [8g, 8g+8); block w owns h-cols [32w, 32w+32) of BOTH layers.
// fp64 recurrence (bool outputs are sign(logit): fp32 order-noise flips them).
__global__ __launch_bounds__(512, 2) void lstm2_head(
    const float* __restrict__ x, const float* __restrict__ W1,
    const float* __restrict__ b1, const float* __restrict__ W2,
    const float* __restrict__ b2, const float* __restrict__ Wo,
    const float* __restrict__ bo, float* __restrict__ out,
    unsigned char* __restrict__ ws)
{
  __shared__ double Alds[6144];   // [kc 0..767][r 0..7] fp64 (48 KB); z aliases kc<256
  __shared__ double WoT[1536];    // Wo [256][6] fp64 (12 KB)

  const int tid = threadIdx.x;
  const int g  = blockIdx.x >> 3;    // 0..31
  const int w  = blockIdx.x & 7;     // 0..7
  const int rb0 = g << 3;            // batch row base

  unsigned* bar = (unsigned*)ws + (g << 4);            // 64B-spaced counters
  double* hbase = (double*)(ws + 4096);
  double* h1g = hbase + (size_t)g * 4096;              // [2 slots][8 r][256]
  double* h2g = hbase + 131072 + (size_t)g * 4096;

  // Wo -> LDS (fp64)
  for (int i = tid; i < 1536; i += 512) WoT[i] = (double)Wo[i];

  // Zero h slot 1 (h(-1)); redundant across the group's 8 blocks, coherent stores.
  for (int i = tid; i < 2048; i += 512) {
    hstore(h1g + 2048 + i, 0.0);
    hstore(h2g + 2048 + i, 0.0);
  }
  light_barrier(bar, 8u);   // barrier #1

  // GEMM mapping: rh = row half (4 rows each), ct = col-task (layer, gate, j)
  const int rh  = tid >> 8;
  const int ct  = tid & 255;
  const int cl  = ct >> 7;                 // 0 = layer1, 1 = layer2
  const int lgc = ct & 127;
  const int wcol = ((lgc >> 5) << 8) + (w << 5) + (lgc & 31);   // gate*256+32w+j
  const float* wbase = (cl ? W2 : W1) + wcol;
  const int k0l = cl << 8;                 // K-window start: 0 or 256

  // Update mapping: one cell per thread: bits [8:6]=row, [5]=layer, [4:0]=hj
  const int ur  = tid >> 6;
  const int ul  = (tid >> 5) & 1;
  const int uhj = tid & 31;
  const float* ubb = ul ? b2 : b1;
  const int ucol = (w << 5) + uhj;
  const double ub_i = (double)ubb[ucol];
  const double ub_j = (double)ubb[256 + ucol];
  const double ub_f = (double)ubb[512 + ucol];
  const double ub_o = (double)ubb[768 + ucol];
  double cst = 0.0;

  // Head: block w==0, wave 4 (tid 256..319); lane = hr*8 + hs (8 rows x 8 k-slices)
  const bool headwave = (w == 0) && (tid >= 256) && (tid < 320);
  const int hl = tid - 256;
  const int hr = hl >> 3, hs = hl & 7;
  double bo_r[6] = {0, 0, 0, 0, 0, 0};
  if (headwave) {
    #pragma unroll
    for (int c = 0; c < 6; ++c) bo_r[c] = (double)bo[c];
  }

  // Phase p: layer1(t=p), layer2(t=p-1), head(t=p-2).
  for (int p = 0; p <= T_ + 1; ++p) {
    const bool doL1 = (p < T_);
    const bool doL2 = (p >= 1) && (p <= T_);
    const int  xp   = doL1 ? p : (T_ - 1);
    const double* h1prev = h1g + (((p + 1) & 1) << 11);   // h1(p-1)
    const double* h2pp   = h2g + ((p & 1) << 11);         // h2(p-2)
    double* h1cur = h1g + ((p & 1) << 11);                // h1(p)
    double* h2cur = h2g + (((p + 1) & 1) << 11);          // h2(p-1)

    // Stage A[kc][r]: [0,256)=x_p (exact cvt), [256,512)=h1(p-1), [512,768)=h2(p-2)
    #pragma unroll
    for (int r = 0; r < 8; ++r) {
      for (int kc = tid; kc < 768; kc += 512) {
        double v;
        if (kc < 256)      v = (double)x[((size_t)(rb0 + r) * T_ + xp) * 256 + kc];
        else if (kc < 512) v = hload(h1prev + (r << 8) + (kc - 256));
        else               v = hload(h2pp + (r << 8) + (kc - 512));
        Alds[(kc << 3) + r] = v;
      }
    }
    __syncthreads();

    // GEMM: thread -> 4 rows x 1 gate-col, K=512 window. Weights streamed from L2
    // (fp32, cvt on use); A broadcast from LDS (all lanes same addr -> free).
    double acc0 = 0.0, acc1 = 0.0, acc2 = 0.0, acc3 = 0.0;
    const bool active = cl ? doL2 : doL1;
    if (active) {
      const double* ap = Alds + (k0l << 3) + (rh << 2);
      const float* wp = wbase;
      #pragma unroll 8
      for (int k5 = 0; k5 < 512; ++k5) {
        double wd = (double)wp[0];
        wp += 1024;
        double2 a01 = *(const double2*)(ap);
        double2 a23 = *(const double2*)(ap + 2);
        ap += 8;
        acc0 = fma(a01.x, wd, acc0);
        acc1 = fma(a01.y, wd, acc1);
        acc2 = fma(a23.x, wd, acc2);
        acc3 = fma(a23.y, wd, acc3);
      }
    }
    __syncthreads();

    // z -> LDS (aliases A's x-region, kc<256): z[row][ct] at row*256+ct
    if (active) {
      double* zb = Alds + (rh << 10) + ct;
      zb[0] = acc0; zb[256] = acc1; zb[512] = acc2; zb[768] = acc3;
    }
    __syncthreads();

    // Cell update: gates (i, j, f, o), forget bias 1.0
    {
      const bool uact = ul ? doL2 : doL1;
      if (uact) {
        const double* zr = Alds + (ur << 8) + (ul << 7);
        double zi = zr[uhj]      + ub_i;
        double zj = zr[32 + uhj] + ub_j;
        double zf = zr[64 + uhj] + ub_f;
        double zo = zr[96 + uhj] + ub_o;
        cst = cst * sigmd(zf + 1.0) + sigmd(zi) * tanh(zj);
        double hv = tanh(cst) * sigmd(zo);
        hstore((ul ? h2cur : h1cur) + (ur << 8) + ucol, hv);
      }
    }

    // Head at t3=p-2 from the staged h2(p-2) (A kc in [512,768), untouched by z)
    const int t3 = p - 2;
    if (t3 >= 0 && headwave) {
      double part[6] = {0, 0, 0, 0, 0, 0};
      const double* ah = Alds + ((512 + (hs << 5)) << 3) + hr;
      const double* wo = WoT + (hs << 5) * 6;
      #pragma unroll 4
      for (int i = 0; i < 32; ++i) {
        double av = ah[i << 3];
        #pragma unroll
        for (int c = 0; c < 6; ++c) part[c] = fma(av, wo[i * 6 + c], part[c]);
      }
      #pragma unroll
      for (int off = 1; off <= 4; off <<= 1) {
        #pragma unroll
        for (int c = 0; c < 6; ++c) part[c] += __shfl_xor(part[c], off, 64);
      }
      if (hs == 0) {
        size_t orow = (((size_t)(rb0 + hr)) << 9) + (size_t)t3;   // b*T + t
        #pragma unroll
        for (int c = 0; c < 6; ++c) {
          double lg = part[c] + bo_r[c];
          out[orow * 6 + c] = (float)lg;
          float pd = (lg > 0.0) ? 1.0f : 0.0f;   // 0.5 < sigmoid(lg) <=> lg > 0
          out[(size_t)786432 + orow * 6 + c] = pd;    // condition
          out[(size_t)1572864 + orow * 6 + c] = pd;   // prediction
        }
      }
    }

    light_barrier(bar, ((unsigned)(p + 2)) << 3);
  }
}

extern "C" void kernel_launch(void* const* d_in, const int* in_sizes, int n_in,
                              void* d_out, int out_size, void* d_ws, size_t ws_size,
                              hipStream_t stream) {
  const float* x  = (const float*)d_in[0];
  const float* W1 = (const float*)d_in[1];
  const float* b1 = (const float*)d_in[2];
  const float* W2 = (const float*)d_in[3];
  const float* b2 = (const float*)d_in[4];
  const float* Wo = (const float*)d_in[5];
  const float* bo = (const float*)d_in[6];
  float* out = (float*)d_out;
  unsigned char* ws = (unsigned char*)d_ws;

  // Zero barrier counters (first 4 KB of ws); part of the captured graph.
  hipMemsetAsync(d_ws, 0, 4096, stream);

  lstm2_head<<<dim3(256), dim3(512), 0, stream>>>(x, W1, b1, W2, b2, Wo, bo, out, ws);
}

// Round 5
// 11933.889 us; speedup vs baseline: 6.8762x; 3.2615x over previous
//
#include <hip/hip_runtime.h>
#include <math.h>

#define T_ 512

__device__ __forceinline__ double sigmd(double v) { return 1.0 / (1.0 + exp(-v)); }

// Coherent (agent-scope, cache-bypassing) 8-byte load/store — no fences needed.
__device__ __forceinline__ double hload(const double* p) {
  unsigned long long u = __hip_atomic_load((const unsigned long long*)p,
                                           __ATOMIC_RELAXED, __HIP_MEMORY_SCOPE_AGENT);
  return __builtin_bit_cast(double, u);
}
__device__ __forceinline__ void hstore(double* p, double v) {
  __hip_atomic_store((unsigned long long*)p, __builtin_bit_cast(unsigned long long, v),
                     __ATOMIC_RELAXED, __HIP_MEMORY_SCOPE_AGENT);
}

// Light group barrier: 8 blocks/group, monotonic counter, no cache-nuking fences.
__device__ __forceinline__ void light_barrier(unsigned* bar, unsigned target) {
  __builtin_amdgcn_s_waitcnt(0);
  __syncthreads();
  if (threadIdx.x == 0) {
    __hip_atomic_fetch_add(bar, 1u, __ATOMIC_RELAXED, __HIP_MEMORY_SCOPE_AGENT);
    while (__hip_atomic_load(bar, __ATOMIC_RELAXED, __HIP_MEMORY_SCOPE_AGENT) < target)
      __builtin_amdgcn_s_sleep(4);
    __asm__ volatile("" ::: "memory");
  }
  __syncthreads();
}

// Grid 256 = 32 groups x 8 blocks; blockIdx = g*8 + w so XCD (blockIdx%8) == w
// caches only col-slice w's 512 KB of weights in its L2. Group g owns batch rows
// [8g, 8g+8); block w owns h-cols [32w, 32w+32) of BOTH layers.
// GEMM: 8 k-teams (1 wave each, 64-k range, no weight duplication); lane covers
// 4 gate-cols x 8 rows (32 fp64 acc). A broadcast from LDS (stride-9 pad).
__global__ __launch_bounds__(512, 2) void lstm2_head(
    const float* __restrict__ x, const float* __restrict__ W1,
    const float* __restrict__ b1, const float* __restrict__ W2,
    const float* __restrict__ b2, const float* __restrict__ Wo,
    const float* __restrict__ bo, float* __restrict__ out,
    unsigned char* __restrict__ ws)
{
  __shared__ double Alds[768 * 9];   // [kc][r] stride 9 (55.3 KB); z aliases [0,4352)

  const int tid = threadIdx.x;
  const int g  = blockIdx.x >> 3;    // 0..31
  const int w  = blockIdx.x & 7;     // 0..7
  const int rb0 = g << 3;

  unsigned* bar = (unsigned*)ws + (g << 4);            // 64B-spaced counters
  double* hbase = (double*)(ws + 4096);
  double* h1g = hbase + (size_t)g * 4096;              // [2 slots][8 r][256]
  double* h2g = hbase + 131072 + (size_t)g * 4096;

  // Zero h(-1) slots (slot 1); redundant across the group's 8 blocks, benign.
  for (int i = tid; i < 2048; i += 512) {
    hstore(h1g + 2048 + i, 0.0);
    hstore(h2g + 2048 + i, 0.0);
  }
  light_barrier(bar, 8u);   // barrier #1

  // ---- GEMM mapping (phase-invariant) ----
  const int lane = tid & 63;
  const int kt   = tid >> 6;               // k-team 0..7
  const int half = lane >> 5;              // 0 = layer1, 1 = layer2
  const int gate = (lane & 31) >> 3;       // 0..3 (i,j,f,o)
  const int jq   = (lane & 7) << 2;        // col-quad within 32-col slice
  const float* wbase0 = (half ? W2 : W1)
      + (size_t)(kt << 6) * 1024 + (gate << 8) + (w << 5) + jq;
  const int kc0 = (half << 8) + (kt << 6); // A kc window start for this lane

  // ---- staging mapping ----
  const int sr  = tid & 7;                 // A-row
  const int skc = tid >> 3;                // 0..63

  // ---- z-reduce mapping ----
  double* zs0 = Alds + (size_t)((kt & 1) * 2176) + ((half << 2) + gate) * 34 + jq;

  // ---- update mapping: one cell per thread ----
  const int L  = tid >> 8;                 // 0 = layer1, 1 = layer2
  const int ur = (tid >> 5) & 7;
  const int hj = tid & 31;
  const int L4t = (L << 2) * 34;
  const float* ubb = L ? b2 : b1;
  const int ucol = (w << 5) + hj;
  const double ub_i = (double)ubb[ucol];
  const double ub_j = (double)ubb[256 + ucol];
  const double ub_f = (double)ubb[512 + ucol];
  const double ub_o = (double)ubb[768 + ucol];
  double cst = 0.0;

  // ---- head (block w==0, wave 0): lane owns h2-cols {lane, 64+lane, 128+, 192+}
  const bool headlane = (w == 0) && (tid < 64);
  float  wo_r[4][6];
  double bo_r[6];
  if (headlane) {
    #pragma unroll
    for (int q = 0; q < 4; ++q)
      #pragma unroll
      for (int c = 0; c < 6; ++c) wo_r[q][c] = Wo[(tid + (q << 6)) * 6 + c];
    #pragma unroll
    for (int c = 0; c < 6; ++c) bo_r[c] = (double)bo[c];
  }

  // Phase p: layer1(t=p), layer2(t=p-1), head(t=p-2).
  #pragma unroll 1
  for (int p = 0; p <= T_ + 1; ++p) {
    const bool doL1 = (p < T_);
    const bool doL2 = (p >= 1) && (p <= T_);
    const int  xp   = doL1 ? p : (T_ - 1);
    const double* h1prev = h1g + (((p + 1) & 1) << 11);
    const double* h2pp   = h2g + ((p & 1) << 11);
    double* h1cur = h1g + ((p & 1) << 11);
    double* h2cur = h2g + (((p + 1) & 1) << 11);

    // ---- Stage A[kc][r]: [0,256)=x_p, [256,512)=h1(p-1), [512,768)=h2(p-2).
    // Batch all global/coherent loads into regs, then LDS writes (one waitcnt).
    {
      double sv[12];
      const float* xb = x + ((size_t)(rb0 + sr) * T_ + xp) * 256 + skc;
      #pragma unroll
      for (int v = 0; v < 4; ++v) sv[v] = (double)xb[v << 6];
      const double* h1b = h1prev + (sr << 8) + skc;
      #pragma unroll
      for (int v = 0; v < 4; ++v) sv[4 + v] = hload(h1b + (v << 6));
      const double* h2b = h2pp + (sr << 8) + skc;
      #pragma unroll
      for (int v = 0; v < 4; ++v) sv[8 + v] = hload(h2b + (v << 6));
      #pragma unroll
      for (int v = 0; v < 12; ++v) Alds[((v << 6) + skc) * 9 + sr] = sv[v];
    }
    __syncthreads();

    // ---- GEMM: wave kt covers k in [64kt, 64kt+64) of its layer's 512-K window.
    double acc[4][8];
    #pragma unroll
    for (int c = 0; c < 4; ++c)
      #pragma unroll
      for (int r = 0; r < 8; ++r) acc[c][r] = 0.0;
    {
      const float* wp = wbase0;
      const double* ap = Alds + kc0 * 9;
      #pragma unroll 4
      for (int s = 0; s < 64; ++s) {
        float4 wv = *(const float4*)wp;
        wp += 1024;
        double a[8];
        #pragma unroll
        for (int r = 0; r < 8; ++r) a[r] = ap[r];
        ap += 9;
        double wd0 = (double)wv.x, wd1 = (double)wv.y;
        double wd2 = (double)wv.z, wd3 = (double)wv.w;
        #pragma unroll
        for (int r = 0; r < 8; ++r) {
          acc[0][r] = fma(a[r], wd0, acc[0][r]);
          acc[1][r] = fma(a[r], wd1, acc[1][r]);
          acc[2][r] = fma(a[r], wd2, acc[2][r]);
          acc[3][r] = fma(a[r], wd3, acc[3][r]);
        }
      }
    }
    __syncthreads();

    // ---- z-reduce: slots s0 (teams 0,2,4,6) and s1 (teams 1,3,5,7) in 4 rounds.
    if (kt < 2) {
      #pragma unroll
      for (int r = 0; r < 8; ++r)
        #pragma unroll
        for (int c = 0; c < 4; ++c) zs0[r * 272 + c] = acc[c][r];
    }
    __syncthreads();
    if ((kt >> 1) == 1) {
      #pragma unroll
      for (int r = 0; r < 8; ++r)
        #pragma unroll
        for (int c = 0; c < 4; ++c) zs0[r * 272 + c] += acc[c][r];
    }
    __syncthreads();
    if ((kt >> 1) == 2) {
      #pragma unroll
      for (int r = 0; r < 8; ++r)
        #pragma unroll
        for (int c = 0; c < 4; ++c) zs0[r * 272 + c] += acc[c][r];
    }
    __syncthreads();
    if ((kt >> 1) == 3) {
      #pragma unroll
      for (int r = 0; r < 8; ++r)
        #pragma unroll
        for (int c = 0; c < 4; ++c) zs0[r * 272 + c] += acc[c][r];
    }
    __syncthreads();

    // ---- Cell update: gates (i,j,f,o), forget bias 1.0. Sum both slots.
    {
      const bool uact = L ? doL2 : doL1;
      if (uact) {
        const double* za = Alds + ur * 272 + L4t + hj;
        double zi = za[0]   + za[2176]       + ub_i;
        double zj = za[34]  + za[2176 + 34]  + ub_j;
        double zf = za[68]  + za[2176 + 68]  + ub_f;
        double zo = za[102] + za[2176 + 102] + ub_o;
        cst = cst * sigmd(zf + 1.0) + sigmd(zi) * tanh(zj);
        double hv = tanh(cst) * sigmd(zo);
        hstore((L ? h2cur : h1cur) + (ur << 8) + ucol, hv);
      }
    }

    // ---- Head at t3 = p-2 from staged h2(p-2) (Alds kc in [512,768), intact).
    const int t3 = p - 2;
    if (t3 >= 0 && headlane) {
      #pragma unroll
      for (int r = 0; r < 8; ++r) {
        double pr[6] = {0, 0, 0, 0, 0, 0};
        #pragma unroll
        for (int q = 0; q < 4; ++q) {
          double hv = Alds[(512 + tid + (q << 6)) * 9 + r];
          #pragma unroll
          for (int c = 0; c < 6; ++c) pr[c] = fma(hv, (double)wo_r[q][c], pr[c]);
        }
        #pragma unroll
        for (int off = 1; off <= 32; off <<= 1)
          #pragma unroll
          for (int c = 0; c < 6; ++c) pr[c] += __shfl_xor(pr[c], off, 64);
        if (tid == 0) {
          size_t orow = (((size_t)(rb0 + r)) << 9) + (size_t)t3;   // b*T + t
          #pragma unroll
          for (int c = 0; c < 6; ++c) {
            double lg = pr[c] + bo_r[c];
            out[orow * 6 + c] = (float)lg;
            float pd = (lg > 0.0) ? 1.0f : 0.0f;   // 0.5 < sigmoid <=> lg > 0
            out[(size_t)786432 + orow * 6 + c] = pd;    // condition
            out[(size_t)1572864 + orow * 6 + c] = pd;   // prediction
          }
        }
      }
    }

    light_barrier(bar, ((unsigned)(p + 2)) << 3);
  }
}

extern "C" void kernel_launch(void* const* d_in, const int* in_sizes, int n_in,
                              void* d_out, int out_size, void* d_ws, size_t ws_size,
                              hipStream_t stream) {
  const float* x  = (const float*)d_in[0];
  const float* W1 = (const float*)d_in[1];
  const float* b1 = (const float*)d_in[2];
  const float* W2 = (const float*)d_in[3];
  const float* b2 = (const float*)d_in[4];
  const float* Wo = (const float*)d_in[5];
  const float* bo = (const float*)d_in[6];
  float* out = (float*)d_out;
  unsigned char* ws = (unsigned char*)d_ws;

  // Zero barrier counters (first 4 KB of ws); part of the captured graph.
  hipMemsetAsync(d_ws, 0, 4096, stream);

  lstm2_head<<<dim3(256), dim3(512), 0, stream>>>(x, W1, b1, W2, b2, Wo, bo, out, ws);
}